// Round 9
// baseline (517.136 us; speedup 1.0000x reference)
//
#include <hip/hip_runtime.h>

#define NSRC 50000
#define NTGT 50000
#define NTOT 100000
#define NE   1600000
#define IND  64
#define HD   128
#define CAP  64        // per-node neighbor capacity in LDS (deg ~ Poisson(16); P(>64) ~ 1e-29)
#define NBKT 8         // level-1 dst-range buckets (XCD-aligned)
#define BNODES 12500   // NTOT / NBKT
#define ECAP 204800    // per-bucket edge capacity (mean 200000, +11 sigma)
#define PCHUNK 1600    // edges per part8 block
#define PBLKS 1000     // NE / PCHUNK
#define NBIN 1563      // ceil(NTOT / 64): level-2 bins of 64 dst nodes

typedef short s16x8 __attribute__((ext_vector_type(8)));
typedef float f32x4 __attribute__((ext_vector_type(4)));

__device__ __forceinline__ ushort f2bf(float f) {
  union { float f; uint u; } v; v.f = f;
  const uint r = v.u + 0x7fffu + ((v.u >> 16) & 1u);
  return (ushort)(r >> 16);
}
__device__ __forceinline__ float bfl(uint v) {
  union { uint u; float f; } c; c.u = v << 16; return c.f;
}
__device__ __forceinline__ float bfh(uint v) {
  union { uint u; float f; } c; c.u = v & 0xffff0000u; return c.f;
}
// floor(d / 12500) for d < 100000 via 2^48 magic (verified at all k*12500 boundaries)
__device__ __forceinline__ uint bkt_of(uint d) {
  return (uint)(((unsigned long long)d * 22517998137ull) >> 48);
}

// ---------------- weight conversion f32 -> bf16 (Wl, Wr) ----------------
__global__ __launch_bounds__(256) void cvt2_kernel(const float* __restrict__ a, ushort* __restrict__ oa,
                                                   const float* __restrict__ b, ushort* __restrict__ ob, int n) {
  int i = blockIdx.x * 256 + threadIdx.x;
  const int stride = gridDim.x * 256;
  for (; i < n; i += stride) { oa[i] = f2bf(a[i]); ob[i] = f2bf(b[i]); }
}

// ---------------- MFMA input projection: out[n][f] = bf16(b[f] + x[n][:] @ W[f][:]) ----------------
// W stays f32 (tiny, L2-hot), converted in-register. Block = 128 rows, 4 waves x 32 rows.
__global__ __launch_bounds__(256) void proj_mfma_kernel(
    const float* __restrict__ x, const float* __restrict__ W,
    const float* __restrict__ b, ushort* __restrict__ out,
    const int count, const int out_base) {
  const int lane = threadIdx.x & 63;
  const int wave = threadIdx.x >> 6;
  const int n0 = blockIdx.x * 128 + wave * 32;
  const int lr = lane & 15;
  const int kc = (lane >> 4) * 8;
  const int rowq = (lane >> 4) * 4;

  s16x8 af[2][2];
#pragma unroll
  for (int r = 0; r < 2; ++r) {
    int ar = n0 + 16 * r + lr;
    if (ar >= count) ar = count - 1;
#pragma unroll
    for (int t = 0; t < 2; ++t) {
      const float* xp = x + (size_t)ar * IND + t * 32 + kc;
      const float4 xa = *(const float4*)(xp);
      const float4 xb = *(const float4*)(xp + 4);
      s16x8 a;
      a[0] = (short)f2bf(xa.x); a[1] = (short)f2bf(xa.y);
      a[2] = (short)f2bf(xa.z); a[3] = (short)f2bf(xa.w);
      a[4] = (short)f2bf(xb.x); a[5] = (short)f2bf(xb.y);
      a[6] = (short)f2bf(xb.z); a[7] = (short)f2bf(xb.w);
      af[r][t] = a;
    }
  }
#pragma unroll
  for (int cf = 0; cf < 8; ++cf) {
    const float* wp = W + (size_t)(cf * 16 + lr) * IND + kc;
    s16x8 w0, w1;
    {
      const float4 wa = *(const float4*)(wp);
      const float4 wb = *(const float4*)(wp + 4);
      const float4 wc = *(const float4*)(wp + 32);
      const float4 wd = *(const float4*)(wp + 36);
      w0[0] = (short)f2bf(wa.x); w0[1] = (short)f2bf(wa.y);
      w0[2] = (short)f2bf(wa.z); w0[3] = (short)f2bf(wa.w);
      w0[4] = (short)f2bf(wb.x); w0[5] = (short)f2bf(wb.y);
      w0[6] = (short)f2bf(wb.z); w0[7] = (short)f2bf(wb.w);
      w1[0] = (short)f2bf(wc.x); w1[1] = (short)f2bf(wc.y);
      w1[2] = (short)f2bf(wc.z); w1[3] = (short)f2bf(wc.w);
      w1[4] = (short)f2bf(wd.x); w1[5] = (short)f2bf(wd.y);
      w1[6] = (short)f2bf(wd.z); w1[7] = (short)f2bf(wd.w);
    }
    f32x4 acc0 = {0.f, 0.f, 0.f, 0.f};
    f32x4 acc1 = {0.f, 0.f, 0.f, 0.f};
    acc0 = __builtin_amdgcn_mfma_f32_16x16x32_bf16(af[0][0], w0, acc0, 0, 0, 0);
    acc1 = __builtin_amdgcn_mfma_f32_16x16x32_bf16(af[1][0], w0, acc1, 0, 0, 0);
    acc0 = __builtin_amdgcn_mfma_f32_16x16x32_bf16(af[0][1], w1, acc0, 0, 0, 0);
    acc1 = __builtin_amdgcn_mfma_f32_16x16x32_bf16(af[1][1], w1, acc1, 0, 0, 0);
    const int col = cf * 16 + lr;
    const float bv = b[col];
#pragma unroll
    for (int r = 0; r < 2; ++r) {
      const f32x4 acc = r ? acc1 : acc0;
#pragma unroll
      for (int q = 0; q < 4; ++q) {
        const int row = n0 + 16 * r + rowq + q;
        if (row < count) out[(size_t)(out_base + row) * HD + col] = f2bf(acc[q] + bv);
      }
    }
  }
}

// ---------------- level-1 partition into 8 dst-range buckets ----------------
// Record = src (17b) | dstLocal (14b) << 17.  ebuf lives in d_out (dead early).
__global__ __launch_bounds__(256) void part8_kernel(const int* __restrict__ src, const int* __restrict__ dst,
                                                    uint* __restrict__ cnt8, uint* __restrict__ ebuf) {
  __shared__ uint lcnt[NBKT];
  __shared__ uint lbase[NBKT];
  const int tid = threadIdx.x;
  const int i0 = blockIdx.x * PCHUNK;
  const int i1 = (i0 + PCHUNK < NE) ? i0 + PCHUNK : NE;
  if (tid < NBKT) lcnt[tid] = 0;
  __syncthreads();
  for (int i = i0 + tid; i < i1; i += 256) {
    const uint b = bkt_of((uint)dst[i]);
    atomicAdd(&lcnt[b], 1u);
  }
  __syncthreads();
  if (tid < NBKT) {
    lbase[tid] = atomicAdd(&cnt8[tid], lcnt[tid]);
    lcnt[tid] = 0;   // reuse as local cursor
  }
  __syncthreads();
  for (int i = i0 + tid; i < i1; i += 256) {
    const uint d = (uint)dst[i];
    const uint b = bkt_of(d);
    const uint pos = lbase[b] + atomicAdd(&lcnt[b], 1u);
    if (pos < ECAP) ebuf[(size_t)b * ECAP + pos] = (uint)src[i] | ((d - b * BNODES) << 17);
  }
}

// ---------------- level-2: count per 64-node bin ----------------
__global__ __launch_bounds__(256) void part2a_kernel(const uint* __restrict__ cnt8, const uint* __restrict__ ebuf,
                                                     uint* __restrict__ bincnt) {
  __shared__ uint hist[NBIN];
  const int tid = threadIdx.x;
  const int b = blockIdx.x & (NBKT - 1);
  const int c = blockIdx.x >> 3;
  int n = (int)cnt8[b]; if (n > ECAP) n = ECAP;
  const int i0 = c * 2048;
  const int i1 = (i0 + 2048 < n) ? i0 + 2048 : n;
  for (int j = tid; j < NBIN; j += 256) hist[j] = 0;
  __syncthreads();
  const uint* eb = ebuf + (size_t)b * ECAP;
  for (int i = i0 + tid; i < i1; i += 256) {
    const uint rec = eb[i];
    const uint d = (uint)(b * BNODES) + (rec >> 17);
    atomicAdd(&hist[d >> 6], 1u);
  }
  __syncthreads();
  for (int j = tid; j < NBIN; j += 256)
    if (hist[j]) atomicAdd(&bincnt[j], hist[j]);
}

// ---------------- exclusive scan of bincnt -> binoff (packed, exact); init bincur ----------------
__global__ __launch_bounds__(256) void scan_kernel(const uint* __restrict__ bincnt,
                                                   uint* __restrict__ binoff, uint* __restrict__ bincur) {
  __shared__ uint lds[256];
  const int tid = threadIdx.x;
  uint v[8]; uint s = 0;
#pragma unroll
  for (int j = 0; j < 8; ++j) {
    const int idx = tid * 8 + j;
    v[j] = (idx < NBIN) ? bincnt[idx] : 0;
    s += v[j];
  }
  lds[tid] = s;
  __syncthreads();
  for (int off = 1; off < 256; off <<= 1) {
    const uint t = (tid >= off) ? lds[tid - off] : 0;
    __syncthreads();
    lds[tid] += t;
    __syncthreads();
  }
  uint run = lds[tid] - s;  // exclusive
#pragma unroll
  for (int j = 0; j < 8; ++j) {
    const int idx = tid * 8 + j;
    if (idx < NBIN) { binoff[idx] = run; bincur[idx] = run; }
    else if (idx == NBIN) binoff[idx] = run;
    run += v[j];
  }
}

// ---------------- level-2 scatter: ebuf -> ebuf2 grouped by bin (ranked, packed) ----------------
// Record out = src (17b) | binLocal (6b) << 17. Blocks are bucket-nested (bid&7) so
// each bin segment is written (mostly) from one XCD -> partial lines merge in its L2.
__global__ __launch_bounds__(256) void part2b_kernel(const uint* __restrict__ cnt8, const uint* __restrict__ ebuf,
                                                     uint* __restrict__ bincur, uint* __restrict__ ebuf2) {
  __shared__ uint hist[NBIN];
  __shared__ uint base[NBIN];
  const int tid = threadIdx.x;
  const int b = blockIdx.x & (NBKT - 1);
  const int c = blockIdx.x >> 3;
  int n = (int)cnt8[b]; if (n > ECAP) n = ECAP;
  const int i0 = c * 2048;
  const int i1 = (i0 + 2048 < n) ? i0 + 2048 : n;
  for (int j = tid; j < NBIN; j += 256) hist[j] = 0;
  __syncthreads();
  const uint* eb = ebuf + (size_t)b * ECAP;
  for (int i = i0 + tid; i < i1; i += 256) {
    const uint rec = eb[i];
    const uint d = (uint)(b * BNODES) + (rec >> 17);
    atomicAdd(&hist[d >> 6], 1u);
  }
  __syncthreads();
  for (int j = tid; j < NBIN; j += 256) {
    if (hist[j]) base[j] = atomicAdd(&bincur[j], hist[j]);
    hist[j] = 0;   // reuse as local cursor
  }
  __syncthreads();
  for (int i = i0 + tid; i < i1; i += 256) {
    const uint rec = eb[i];
    const uint d = (uint)(b * BNODES) + (rec >> 17);
    const uint bin = d >> 6;
    const uint pos = base[bin] + atomicAdd(&hist[bin], 1u);
    ebuf2[pos] = (rec & 0x1FFFFu) | ((d & 63u) << 17);
  }
}

// ---------------- fused mean-aggregation + dual GEMM per 64-node bin ----------------
// 256 threads = 4 waves. Phase A: LDS-scatter the bin's packed edge slice into
// per-node lists. Phase B: gather+mean (4 groups of 16 lanes, 4 loads in flight),
// result packed bf16 into LDS aggL[64][136] (row stride 272B -> 2-way bank alias max).
// Phase C: dual GEMM for the bin's 64 rows: out = agg@Wl^T + bl + h_self@Wr^T.
// NOT in-place: reads hin (gather + self rows), writes outv (ping-pong buffer).
__global__ __launch_bounds__(256) void aggemm_kernel(
    const ushort* __restrict__ hin, void* __restrict__ outv,
    const uint* __restrict__ binoff, const uint* __restrict__ ebuf2,
    const ushort* __restrict__ Wl, const float* __restrict__ bl,
    const ushort* __restrict__ Wr, const int relu, const int f32out) {
  __shared__ uint slotL[64][CAP];      // 16 KB
  __shared__ uint cntL[64];
  __shared__ ushort aggL[64][136];     // 17 KB (+8 col pad: rows advance 4 banks)
  const int tid = threadIdx.x;
  const int lane = tid & 63;
  const int wv = tid >> 6;          // 0..3
  const int g = lane >> 4;          // 0..3
  const int l16 = lane & 15;
  if (tid < 64) cntL[tid] = 0;
  __syncthreads();
  // ---- phase A ----
  const int e0 = (int)binoff[blockIdx.x];
  const int e1 = (int)binoff[blockIdx.x + 1];
  for (int i = e0 + tid; i < e1; i += 256) {
    const uint rec = ebuf2[i];
    const uint dl = rec >> 17;
    const uint pos = atomicAdd(&cntL[dl], 1u);
    if (pos < CAP) slotL[dl][pos] = rec & 0x1FFFFu;
  }
  __syncthreads();
  // ---- phase B ----
  const uint4* hp = (const uint4*)hin;   // row = 16 uint4 (128 bf16)
  const int nbase = blockIdx.x * 64;
#pragma unroll 1
  for (int t = 0; t < 16; ++t) {
    const int nl = wv * 16 + t;
    const int n = nbase + nl;
    if (n >= NTOT) break;   // wave-uniform
    const int deg = (int)cntL[nl];
    const int m = deg < CAP ? deg : CAP;
    float a0 = 0.f, a1 = 0.f, a2 = 0.f, a3 = 0.f, a4 = 0.f, a5 = 0.f, a6 = 0.f, a7 = 0.f;
    for (int ib = g; ib < m; ib += 16) {
      int rows[4];
      uint4 vv[4];
#pragma unroll
      for (int u = 0; u < 4; ++u) {
        const int idx = ib + 4 * u;
        rows[u] = (idx < m) ? (int)slotL[nl][idx] : -1;   // LDS broadcast (16 lanes)
      }
#pragma unroll
      for (int u = 0; u < 4; ++u)
        if (rows[u] >= 0) vv[u] = hp[(size_t)rows[u] * 16 + l16];
#pragma unroll
      for (int u = 0; u < 4; ++u) {
        if (rows[u] >= 0) {
          a0 += bfl(vv[u].x); a1 += bfh(vv[u].x);
          a2 += bfl(vv[u].y); a3 += bfh(vv[u].y);
          a4 += bfl(vv[u].z); a5 += bfh(vv[u].z);
          a6 += bfl(vv[u].w); a7 += bfh(vv[u].w);
        }
      }
    }
#pragma unroll
    for (int off = 16; off < 64; off <<= 1) {
      a0 += __shfl_xor(a0, off); a1 += __shfl_xor(a1, off);
      a2 += __shfl_xor(a2, off); a3 += __shfl_xor(a3, off);
      a4 += __shfl_xor(a4, off); a5 += __shfl_xor(a5, off);
      a6 += __shfl_xor(a6, off); a7 += __shfl_xor(a7, off);
    }
    if (g == 0) {
      const float sc = 1.0f / (float)(deg > 1 ? deg : 1);
      uint4 o;
      o.x = (uint)f2bf(a0 * sc) | ((uint)f2bf(a1 * sc) << 16);
      o.y = (uint)f2bf(a2 * sc) | ((uint)f2bf(a3 * sc) << 16);
      o.z = (uint)f2bf(a4 * sc) | ((uint)f2bf(a5 * sc) << 16);
      o.w = (uint)f2bf(a6 * sc) | ((uint)f2bf(a7 * sc) << 16);
      *(uint4*)&aggL[nl][l16 * 8] = o;   // 16B aligned (272 = 17*16)
    }
  }
  __syncthreads();
  // ---- phase C: dual GEMM over the bin's 64 rows (wave wv owns rows wv*16..+15) ----
  const int lr = l16;
  const int kc = g * 8;
  const int rowq = g * 4;
  const int myrow = wv * 16 + lr;
  int gr = nbase + myrow;
  if (gr >= NTOT) gr = NTOT - 1;       // clamped lanes never store
  s16x8 af[4], hf[4];
#pragma unroll
  for (int t = 0; t < 4; ++t) {
    af[t] = *(const s16x8*)&aggL[myrow][t * 32 + kc];
    hf[t] = *(const s16x8*)(hin + (size_t)gr * HD + t * 32 + kc);
  }
#pragma unroll
  for (int cf = 0; cf < 8; ++cf) {
    const ushort* wlp = Wl + (size_t)(cf * 16 + lr) * HD + kc;
    const ushort* wrp = Wr + (size_t)(cf * 16 + lr) * HD + kc;
    s16x8 wl[4], wr[4];
#pragma unroll
    for (int t = 0; t < 4; ++t) {
      wl[t] = *(const s16x8*)(wlp + t * 32);
      wr[t] = *(const s16x8*)(wrp + t * 32);
    }
    f32x4 acc = {0.f, 0.f, 0.f, 0.f};
#pragma unroll
    for (int t = 0; t < 4; ++t) {
      acc = __builtin_amdgcn_mfma_f32_16x16x32_bf16(af[t], wl[t], acc, 0, 0, 0);
      acc = __builtin_amdgcn_mfma_f32_16x16x32_bf16(hf[t], wr[t], acc, 0, 0, 0);
    }
    const int col = cf * 16 + lr;
    const float bv = bl[col];
#pragma unroll
    for (int q = 0; q < 4; ++q) {
      const int orow = nbase + wv * 16 + rowq + q;
      if (orow < NTOT) {
        float v = acc[q] + bv;
        if (relu && v < 0.f) v = 0.f;
        if (f32out) ((float*)outv)[(size_t)orow * HD + col] = v;
        else        ((ushort*)outv)[(size_t)orow * HD + col] = f2bf(v);
      }
    }
  }
}

extern "C" void kernel_launch(void* const* d_in, const int* in_sizes, int n_in,
                              void* d_out, int out_size, void* d_ws, size_t ws_size,
                              hipStream_t stream) {
  const float* src_x = (const float*)d_in[0];
  const float* tgt_x = (const float*)d_in[1];
  const int*   eidx  = (const int*)d_in[2];
  const float* Wsrc  = (const float*)d_in[3];
  const float* bsrc  = (const float*)d_in[4];
  const float* Wtgt  = (const float*)d_in[5];
  const float* btgt  = (const float*)d_in[6];
  const float* Wl    = (const float*)d_in[7];
  const float* bl    = (const float*)d_in[8];
  const float* Wr    = (const float*)d_in[9];
  float* out = (float*)d_out;
  (void)in_sizes; (void)n_in; (void)out_size; (void)ws_size;

  // ws total ~58 MB (<= round-2 proven ~59.4 MB)
  char* ws = (char*)d_ws;
  size_t off = 0;
  auto alloc = [&](size_t bytes) -> void* {
    void* p = (void*)(ws + off);
    off = (off + bytes + 511) & ~(size_t)511;
    return p;
  };
  ushort* hbuf   = (ushort*)alloc((size_t)NTOT * HD * sizeof(ushort));  // 25.6 MB
  ushort* abuf   = (ushort*)alloc((size_t)NTOT * HD * sizeof(ushort));  // 25.6 MB
  ushort* wlb    = (ushort*)alloc((size_t)3 * HD * HD * sizeof(ushort));
  ushort* wrb    = (ushort*)alloc((size_t)3 * HD * HD * sizeof(ushort));
  uint*   cnt8   = (uint*)alloc(NBKT * sizeof(uint));
  uint*   bincnt = (uint*)alloc(NBIN * sizeof(uint));
  uint*   binoff = (uint*)alloc((NBIN + 1) * sizeof(uint));
  uint*   bincur = (uint*)alloc(NBIN * sizeof(uint));
  uint*   ebuf2  = (uint*)alloc((size_t)NE * sizeof(uint));             // 6.4 MB (packed)
  // ebuf (level-1 buckets, 6.55 MB) lives in d_out; dead after part2b, long before
  // the final aggemm writes d_out.
  uint*   ebuf   = (uint*)d_out;

  const int* src_idx = eidx;
  const int* dst_idx = eidx + NE;

  hipMemsetAsync(cnt8, 0, NBKT * sizeof(uint), stream);
  hipMemsetAsync(bincnt, 0, NBIN * sizeof(uint), stream);

  cvt2_kernel<<<192, 256, 0, stream>>>(Wl, wlb, Wr, wrb, 3 * HD * HD);

  proj_mfma_kernel<<<(NSRC + 127) / 128, 256, 0, stream>>>(src_x, Wsrc, bsrc, hbuf, NSRC, 0);
  proj_mfma_kernel<<<(NTGT + 127) / 128, 256, 0, stream>>>(tgt_x, Wtgt, btgt, hbuf, NTGT, NSRC);

  part8_kernel<<<PBLKS, 256, 0, stream>>>(src_idx, dst_idx, cnt8, ebuf);
  part2a_kernel<<<800, 256, 0, stream>>>(cnt8, ebuf, bincnt);
  scan_kernel<<<1, 256, 0, stream>>>(bincnt, binoff, bincur);
  part2b_kernel<<<800, 256, 0, stream>>>(cnt8, ebuf, bincur, ebuf2);

  // layer 0: hbuf -> abuf (relu)
  aggemm_kernel<<<NBIN, 256, 0, stream>>>(hbuf, abuf, binoff, ebuf2, wlb, bl, wrb, 1, 0);
  // layer 1: abuf -> hbuf (relu)
  aggemm_kernel<<<NBIN, 256, 0, stream>>>(abuf, hbuf, binoff, ebuf2, wlb + HD * HD, bl + HD, wrb + HD * HD, 1, 0);
  // layer 2: hbuf -> d_out (f32, no relu); ebuf dead here
  aggemm_kernel<<<NBIN, 256, 0, stream>>>(hbuf, out, binoff, ebuf2, wlb + 2 * HD * HD, bl + 2 * HD, wrb + 2 * HD * HD, 0, 1);
}

// Round 10
// 410.943 us; speedup vs baseline: 1.2584x; 1.2584x over previous
//
#include <hip/hip_runtime.h>

#define NSRC 50000
#define NTGT 50000
#define NTOT 100000
#define NE   1600000
#define IND  64
#define HD   128
#define CAP  64        // per-node neighbor capacity in LDS (deg ~ Poisson(16); P(>64) ~ 1e-29)
#define NBKT 8         // level-1 dst-range buckets (XCD-aligned)
#define BNODES 12500   // NTOT / NBKT
#define ECAP 204800    // per-bucket edge capacity (mean 200000, +11 sigma)
#define PCHUNK 1600    // edges per part8 block
#define PBLKS 1000     // NE / PCHUNK
#define NBIN 3125      // NTOT / 32: level-2 bins of 32 dst nodes (exact, no tail)
#define BINSZ 32
#define GEMM_GRID 782  // ceil(NTOT / 128)

typedef short s16x8 __attribute__((ext_vector_type(8)));
typedef float f32x4 __attribute__((ext_vector_type(4)));

__device__ __forceinline__ ushort f2bf(float f) {
  union { float f; uint u; } v; v.f = f;
  const uint r = v.u + 0x7fffu + ((v.u >> 16) & 1u);
  return (ushort)(r >> 16);
}
__device__ __forceinline__ float bfl(uint v) {
  union { uint u; float f; } c; c.u = v << 16; return c.f;
}
__device__ __forceinline__ float bfh(uint v) {
  union { uint u; float f; } c; c.u = v & 0xffff0000u; return c.f;
}
// floor(d / 12500) for d < 100000 via 2^48 magic (verified at all k*12500 boundaries)
__device__ __forceinline__ uint bkt_of(uint d) {
  return (uint)(((unsigned long long)d * 22517998137ull) >> 48);
}

// ---------------- weight conversion f32 -> bf16 (Wl, Wr) ----------------
__global__ __launch_bounds__(256) void cvt2_kernel(const float* __restrict__ a, ushort* __restrict__ oa,
                                                   const float* __restrict__ b, ushort* __restrict__ ob, int n) {
  int i = blockIdx.x * 256 + threadIdx.x;
  const int stride = gridDim.x * 256;
  for (; i < n; i += stride) { oa[i] = f2bf(a[i]); ob[i] = f2bf(b[i]); }
}

// ---------------- MFMA input projection: out[n][f] = bf16(b[f] + x[n][:] @ W[f][:]) ----------------
// W stays f32 (tiny, L2-hot), converted in-register. Block = 128 rows, 4 waves x 32 rows.
__global__ __launch_bounds__(256) void proj_mfma_kernel(
    const float* __restrict__ x, const float* __restrict__ W,
    const float* __restrict__ b, ushort* __restrict__ out,
    const int count, const int out_base) {
  const int lane = threadIdx.x & 63;
  const int wave = threadIdx.x >> 6;
  const int n0 = blockIdx.x * 128 + wave * 32;
  const int lr = lane & 15;
  const int kc = (lane >> 4) * 8;
  const int rowq = (lane >> 4) * 4;

  s16x8 af[2][2];
#pragma unroll
  for (int r = 0; r < 2; ++r) {
    int ar = n0 + 16 * r + lr;
    if (ar >= count) ar = count - 1;
#pragma unroll
    for (int t = 0; t < 2; ++t) {
      const float* xp = x + (size_t)ar * IND + t * 32 + kc;
      const float4 xa = *(const float4*)(xp);
      const float4 xb = *(const float4*)(xp + 4);
      s16x8 a;
      a[0] = (short)f2bf(xa.x); a[1] = (short)f2bf(xa.y);
      a[2] = (short)f2bf(xa.z); a[3] = (short)f2bf(xa.w);
      a[4] = (short)f2bf(xb.x); a[5] = (short)f2bf(xb.y);
      a[6] = (short)f2bf(xb.z); a[7] = (short)f2bf(xb.w);
      af[r][t] = a;
    }
  }
#pragma unroll
  for (int cf = 0; cf < 8; ++cf) {
    const float* wp = W + (size_t)(cf * 16 + lr) * IND + kc;
    s16x8 w0, w1;
    {
      const float4 wa = *(const float4*)(wp);
      const float4 wb = *(const float4*)(wp + 4);
      const float4 wc = *(const float4*)(wp + 32);
      const float4 wd = *(const float4*)(wp + 36);
      w0[0] = (short)f2bf(wa.x); w0[1] = (short)f2bf(wa.y);
      w0[2] = (short)f2bf(wa.z); w0[3] = (short)f2bf(wa.w);
      w0[4] = (short)f2bf(wb.x); w0[5] = (short)f2bf(wb.y);
      w0[6] = (short)f2bf(wb.z); w0[7] = (short)f2bf(wb.w);
      w1[0] = (short)f2bf(wc.x); w1[1] = (short)f2bf(wc.y);
      w1[2] = (short)f2bf(wc.z); w1[3] = (short)f2bf(wc.w);
      w1[4] = (short)f2bf(wd.x); w1[5] = (short)f2bf(wd.y);
      w1[6] = (short)f2bf(wd.z); w1[7] = (short)f2bf(wd.w);
    }
    f32x4 acc0 = {0.f, 0.f, 0.f, 0.f};
    f32x4 acc1 = {0.f, 0.f, 0.f, 0.f};
    acc0 = __builtin_amdgcn_mfma_f32_16x16x32_bf16(af[0][0], w0, acc0, 0, 0, 0);
    acc1 = __builtin_amdgcn_mfma_f32_16x16x32_bf16(af[1][0], w0, acc1, 0, 0, 0);
    acc0 = __builtin_amdgcn_mfma_f32_16x16x32_bf16(af[0][1], w1, acc0, 0, 0, 0);
    acc1 = __builtin_amdgcn_mfma_f32_16x16x32_bf16(af[1][1], w1, acc1, 0, 0, 0);
    const int col = cf * 16 + lr;
    const float bv = b[col];
#pragma unroll
    for (int r = 0; r < 2; ++r) {
      const f32x4 acc = r ? acc1 : acc0;
#pragma unroll
      for (int q = 0; q < 4; ++q) {
        const int row = n0 + 16 * r + rowq + q;
        if (row < count) out[(size_t)(out_base + row) * HD + col] = f2bf(acc[q] + bv);
      }
    }
  }
}

// ---------------- level-1 partition into 8 dst-range buckets ----------------
// Record = src (17b) | dstLocal (14b) << 17.  ebuf lives in d_out (dead early).
__global__ __launch_bounds__(256) void part8_kernel(const int* __restrict__ src, const int* __restrict__ dst,
                                                    uint* __restrict__ cnt8, uint* __restrict__ ebuf) {
  __shared__ uint lcnt[NBKT];
  __shared__ uint lbase[NBKT];
  const int tid = threadIdx.x;
  const int i0 = blockIdx.x * PCHUNK;
  const int i1 = (i0 + PCHUNK < NE) ? i0 + PCHUNK : NE;
  if (tid < NBKT) lcnt[tid] = 0;
  __syncthreads();
  for (int i = i0 + tid; i < i1; i += 256) {
    const uint b = bkt_of((uint)dst[i]);
    atomicAdd(&lcnt[b], 1u);
  }
  __syncthreads();
  if (tid < NBKT) {
    lbase[tid] = atomicAdd(&cnt8[tid], lcnt[tid]);
    lcnt[tid] = 0;   // reuse as local cursor
  }
  __syncthreads();
  for (int i = i0 + tid; i < i1; i += 256) {
    const uint d = (uint)dst[i];
    const uint b = bkt_of(d);
    const uint pos = lbase[b] + atomicAdd(&lcnt[b], 1u);
    if (pos < ECAP) ebuf[(size_t)b * ECAP + pos] = (uint)src[i] | ((d - b * BNODES) << 17);
  }
}

// ---------------- level-2: count per 32-node bin ----------------
__global__ __launch_bounds__(256) void part2a_kernel(const uint* __restrict__ cnt8, const uint* __restrict__ ebuf,
                                                     uint* __restrict__ bincnt) {
  __shared__ uint hist[NBIN];   // 12.5 KB
  const int tid = threadIdx.x;
  const int b = blockIdx.x & (NBKT - 1);
  const int c = blockIdx.x >> 3;
  int n = (int)cnt8[b]; if (n > ECAP) n = ECAP;
  const int i0 = c * 2048;
  const int i1 = (i0 + 2048 < n) ? i0 + 2048 : n;
  for (int j = tid; j < NBIN; j += 256) hist[j] = 0;
  __syncthreads();
  const uint* eb = ebuf + (size_t)b * ECAP;
  for (int i = i0 + tid; i < i1; i += 256) {
    const uint rec = eb[i];
    const uint d = (uint)(b * BNODES) + (rec >> 17);
    atomicAdd(&hist[d >> 5], 1u);
  }
  __syncthreads();
  for (int j = tid; j < NBIN; j += 256)
    if (hist[j]) atomicAdd(&bincnt[j], hist[j]);
}

// ---------------- exclusive scan of bincnt -> binoff (packed, exact); init bincur ----------------
__global__ __launch_bounds__(256) void scan_kernel(const uint* __restrict__ bincnt,
                                                   uint* __restrict__ binoff, uint* __restrict__ bincur) {
  __shared__ uint lds[256];
  const int tid = threadIdx.x;
  uint v[16]; uint s = 0;
#pragma unroll
  for (int j = 0; j < 16; ++j) {
    const int idx = tid * 16 + j;
    v[j] = (idx < NBIN) ? bincnt[idx] : 0;
    s += v[j];
  }
  lds[tid] = s;
  __syncthreads();
  for (int off = 1; off < 256; off <<= 1) {
    const uint t = (tid >= off) ? lds[tid - off] : 0;
    __syncthreads();
    lds[tid] += t;
    __syncthreads();
  }
  uint run = lds[tid] - s;  // exclusive
#pragma unroll
  for (int j = 0; j < 16; ++j) {
    const int idx = tid * 16 + j;
    if (idx < NBIN) { binoff[idx] = run; bincur[idx] = run; }
    else if (idx == NBIN) binoff[idx] = run;
    run += v[j];
  }
}

// ---------------- level-2 scatter: ebuf -> ebuf2 grouped by bin (ranked, packed) ----------------
// Record out = src (17b) | binLocal (5b) << 17. Blocks are bucket-nested (bid&7) so
// each bin segment is written (mostly) from one XCD -> partial lines merge in its L2.
__global__ __launch_bounds__(256) void part2b_kernel(const uint* __restrict__ cnt8, const uint* __restrict__ ebuf,
                                                     uint* __restrict__ bincur, uint* __restrict__ ebuf2) {
  __shared__ uint hist[NBIN];   // 12.5 KB
  __shared__ uint base[NBIN];   // 12.5 KB
  const int tid = threadIdx.x;
  const int b = blockIdx.x & (NBKT - 1);
  const int c = blockIdx.x >> 3;
  int n = (int)cnt8[b]; if (n > ECAP) n = ECAP;
  const int i0 = c * 2048;
  const int i1 = (i0 + 2048 < n) ? i0 + 2048 : n;
  for (int j = tid; j < NBIN; j += 256) hist[j] = 0;
  __syncthreads();
  const uint* eb = ebuf + (size_t)b * ECAP;
  for (int i = i0 + tid; i < i1; i += 256) {
    const uint rec = eb[i];
    const uint d = (uint)(b * BNODES) + (rec >> 17);
    atomicAdd(&hist[d >> 5], 1u);
  }
  __syncthreads();
  for (int j = tid; j < NBIN; j += 256) {
    if (hist[j]) base[j] = atomicAdd(&bincur[j], hist[j]);
    hist[j] = 0;   // reuse as local cursor
  }
  __syncthreads();
  for (int i = i0 + tid; i < i1; i += 256) {
    const uint rec = eb[i];
    const uint d = (uint)(b * BNODES) + (rec >> 17);
    const uint bin = d >> 5;
    const uint pos = base[bin] + atomicAdd(&hist[bin], 1u);
    ebuf2[pos] = (rec & 0x1FFFFu) | ((d & 31u) << 17);
  }
}

// ---------------- mean aggregation: one block per 32-node bin; neighbor lists in LDS ----------------
// 256 threads = 4 waves x 8 nodes each. Small LDS (8.4 KB) -> 8 blocks/CU (thread cap),
// grid 3125 = 12.2 blocks/CU -> high occupancy for gather latency hiding.
// Phase B: per node, 4 groups of 16 lanes gather full 256B h-rows, 4 loads in flight.
__global__ __launch_bounds__(256) void agg3_kernel(const ushort* __restrict__ h, ushort* __restrict__ agg,
                                                   const uint* __restrict__ binoff, const uint* __restrict__ ebuf2) {
  __shared__ uint slotL[BINSZ][CAP];   // 8 KB
  __shared__ uint cntL[BINSZ];
  const int tid = threadIdx.x;
  const int lane = tid & 63;
  const int wv = tid >> 6;          // 0..3
  const int g = lane >> 4;          // 0..3
  const int l16 = lane & 15;
  if (tid < BINSZ) cntL[tid] = 0;
  __syncthreads();
  const int e0 = (int)binoff[blockIdx.x];
  const int e1 = (int)binoff[blockIdx.x + 1];
  for (int i = e0 + tid; i < e1; i += 256) {
    const uint rec = ebuf2[i];
    const uint dl = rec >> 17;
    const uint pos = atomicAdd(&cntL[dl], 1u);
    if (pos < CAP) slotL[dl][pos] = rec & 0x1FFFFu;
  }
  __syncthreads();
  const uint4* hp = (const uint4*)h;   // row = 16 uint4 (128 bf16)
  uint4* aggp = (uint4*)agg;
  const int nbase = blockIdx.x * BINSZ;
#pragma unroll 1
  for (int t = 0; t < 8; ++t) {
    const int nl = wv * 8 + t;
    const int n = nbase + nl;       // always < NTOT (3125*32 = 100000 exact)
    const int deg = (int)cntL[nl];
    const int m = deg < CAP ? deg : CAP;
    float a0 = 0.f, a1 = 0.f, a2 = 0.f, a3 = 0.f, a4 = 0.f, a5 = 0.f, a6 = 0.f, a7 = 0.f;
    for (int ib = g; ib < m; ib += 16) {
      int rows[4];
      uint4 vv[4];
#pragma unroll
      for (int u = 0; u < 4; ++u) {
        const int idx = ib + 4 * u;
        rows[u] = (idx < m) ? (int)slotL[nl][idx] : -1;   // LDS broadcast (16 lanes)
      }
#pragma unroll
      for (int u = 0; u < 4; ++u)
        if (rows[u] >= 0) vv[u] = hp[(size_t)rows[u] * 16 + l16];
#pragma unroll
      for (int u = 0; u < 4; ++u) {
        if (rows[u] >= 0) {
          a0 += bfl(vv[u].x); a1 += bfh(vv[u].x);
          a2 += bfl(vv[u].y); a3 += bfh(vv[u].y);
          a4 += bfl(vv[u].z); a5 += bfh(vv[u].z);
          a6 += bfl(vv[u].w); a7 += bfh(vv[u].w);
        }
      }
    }
#pragma unroll
    for (int off = 16; off < 64; off <<= 1) {
      a0 += __shfl_xor(a0, off); a1 += __shfl_xor(a1, off);
      a2 += __shfl_xor(a2, off); a3 += __shfl_xor(a3, off);
      a4 += __shfl_xor(a4, off); a5 += __shfl_xor(a5, off);
      a6 += __shfl_xor(a6, off); a7 += __shfl_xor(a7, off);
    }
    if (g == 0) {
      const float sc = 1.0f / (float)(deg > 1 ? deg : 1);
      uint4 o;
      o.x = (uint)f2bf(a0 * sc) | ((uint)f2bf(a1 * sc) << 16);
      o.y = (uint)f2bf(a2 * sc) | ((uint)f2bf(a3 * sc) << 16);
      o.z = (uint)f2bf(a4 * sc) | ((uint)f2bf(a5 * sc) << 16);
      o.w = (uint)f2bf(a6 * sc) | ((uint)f2bf(a7 * sc) << 16);
      aggp[(size_t)n * 16 + l16] = o;
    }
  }
}

// ---------------- MFMA dual GEMM: out = A@Wl^T + bl + Hm@Wr^T (opt relu, opt f32 out) ----------------
// Block = 128 rows, 4 waves; each wave owns 32 rows x all 128 cols. No LDS.
// In-place safe (out may alias A): each wave loads its own 32 rows into registers
// before any store; no __restrict__ on aliasing pointers.
__global__ __launch_bounds__(256) void mfma_gemm_kernel(
    const ushort* A, const ushort* Hm,
    const ushort* __restrict__ Wl, const float* __restrict__ bl,
    const ushort* __restrict__ Wr, void* outv,
    const int relu, const int f32out) {
  const int lane = threadIdx.x & 63;
  const int wave = threadIdx.x >> 6;
  const int n0 = blockIdx.x * 128 + wave * 32;
  const int lr = lane & 15;            // A-frag row / B-frag col / C-frag col
  const int kc = (lane >> 4) * 8;      // k-chunk within 32-wide K step
  const int rowq = (lane >> 4) * 4;    // C-frag row base

  s16x8 af[2][4], hf[2][4];
#pragma unroll
  for (int r = 0; r < 2; ++r) {
    int ar = n0 + 16 * r + lr;
    if (ar >= NTOT) ar = NTOT - 1;     // clamped lanes never store
    const ushort* ap = A + (size_t)ar * HD + kc;
    const ushort* hp = Hm + (size_t)ar * HD + kc;
#pragma unroll
    for (int t = 0; t < 4; ++t) {
      af[r][t] = *(const s16x8*)(ap + t * 32);
      hf[r][t] = *(const s16x8*)(hp + t * 32);
    }
  }

#pragma unroll
  for (int cf = 0; cf < 8; ++cf) {
    const ushort* wlp = Wl + (size_t)(cf * 16 + lr) * HD + kc;
    const ushort* wrp = Wr + (size_t)(cf * 16 + lr) * HD + kc;
    s16x8 wl[4], wr[4];
#pragma unroll
    for (int t = 0; t < 4; ++t) {
      wl[t] = *(const s16x8*)(wlp + t * 32);
      wr[t] = *(const s16x8*)(wrp + t * 32);
    }
    f32x4 acc0 = {0.f, 0.f, 0.f, 0.f};
    f32x4 acc1 = {0.f, 0.f, 0.f, 0.f};
#pragma unroll
    for (int t = 0; t < 4; ++t) {
      acc0 = __builtin_amdgcn_mfma_f32_16x16x32_bf16(af[0][t], wl[t], acc0, 0, 0, 0);
      acc1 = __builtin_amdgcn_mfma_f32_16x16x32_bf16(af[1][t], wl[t], acc1, 0, 0, 0);
      acc0 = __builtin_amdgcn_mfma_f32_16x16x32_bf16(hf[0][t], wr[t], acc0, 0, 0, 0);
      acc1 = __builtin_amdgcn_mfma_f32_16x16x32_bf16(hf[1][t], wr[t], acc1, 0, 0, 0);
    }
    const float bv = bl[cf * 16 + lr];
    const int col = cf * 16 + lr;
#pragma unroll
    for (int r = 0; r < 2; ++r) {
      const f32x4 acc = r ? acc1 : acc0;
#pragma unroll
      for (int q = 0; q < 4; ++q) {
        const int row = n0 + 16 * r + rowq + q;
        if (row < NTOT) {
          float v = acc[q] + bv;
          if (relu && v < 0.f) v = 0.f;
          if (f32out) ((float*)outv)[(size_t)row * HD + col] = v;
          else        ((ushort*)outv)[(size_t)row * HD + col] = f2bf(v);
        }
      }
    }
  }
}

extern "C" void kernel_launch(void* const* d_in, const int* in_sizes, int n_in,
                              void* d_out, int out_size, void* d_ws, size_t ws_size,
                              hipStream_t stream) {
  const float* src_x = (const float*)d_in[0];
  const float* tgt_x = (const float*)d_in[1];
  const int*   eidx  = (const int*)d_in[2];
  const float* Wsrc  = (const float*)d_in[3];
  const float* bsrc  = (const float*)d_in[4];
  const float* Wtgt  = (const float*)d_in[5];
  const float* btgt  = (const float*)d_in[6];
  const float* Wl    = (const float*)d_in[7];
  const float* bl    = (const float*)d_in[8];
  const float* Wr    = (const float*)d_in[9];
  float* out = (float*)d_out;
  (void)in_sizes; (void)n_in; (void)out_size; (void)ws_size;

  // ws total ~58 MB (<= round-2 proven ~59.4 MB)
  char* ws = (char*)d_ws;
  size_t off = 0;
  auto alloc = [&](size_t bytes) -> void* {
    void* p = (void*)(ws + off);
    off = (off + bytes + 511) & ~(size_t)511;
    return p;
  };
  ushort* hbuf   = (ushort*)alloc((size_t)NTOT * HD * sizeof(ushort));  // 25.6 MB
  ushort* abuf   = (ushort*)alloc((size_t)NTOT * HD * sizeof(ushort));  // 25.6 MB
  ushort* wlb    = (ushort*)alloc((size_t)3 * HD * HD * sizeof(ushort));
  ushort* wrb    = (ushort*)alloc((size_t)3 * HD * HD * sizeof(ushort));
  uint*   cnt8   = (uint*)alloc(NBKT * sizeof(uint));
  uint*   bincnt = (uint*)alloc(NBIN * sizeof(uint));
  uint*   binoff = (uint*)alloc((NBIN + 1) * sizeof(uint));
  uint*   bincur = (uint*)alloc(NBIN * sizeof(uint));
  uint*   ebuf2  = (uint*)alloc((size_t)NE * sizeof(uint));             // 6.4 MB (packed)
  // ebuf (level-1 buckets, 6.55 MB) lives in d_out; dead after part2b, long before
  // the final gemm writes d_out.
  uint*   ebuf   = (uint*)d_out;

  const int* src_idx = eidx;
  const int* dst_idx = eidx + NE;

  hipMemsetAsync(cnt8, 0, NBKT * sizeof(uint), stream);
  hipMemsetAsync(bincnt, 0, NBIN * sizeof(uint), stream);

  cvt2_kernel<<<192, 256, 0, stream>>>(Wl, wlb, Wr, wrb, 3 * HD * HD);

  proj_mfma_kernel<<<(NSRC + 127) / 128, 256, 0, stream>>>(src_x, Wsrc, bsrc, hbuf, NSRC, 0);
  proj_mfma_kernel<<<(NTGT + 127) / 128, 256, 0, stream>>>(tgt_x, Wtgt, btgt, hbuf, NTGT, NSRC);

  part8_kernel<<<PBLKS, 256, 0, stream>>>(src_idx, dst_idx, cnt8, ebuf);
  part2a_kernel<<<800, 256, 0, stream>>>(cnt8, ebuf, bincnt);
  scan_kernel<<<1, 256, 0, stream>>>(bincnt, binoff, bincur);
  part2b_kernel<<<800, 256, 0, stream>>>(cnt8, ebuf, bincur, ebuf2);

  // layer 0: h0 = hbuf; agg -> abuf; h1 = abuf (in place)
  agg3_kernel<<<NBIN, 256, 0, stream>>>(hbuf, abuf, binoff, ebuf2);
  mfma_gemm_kernel<<<GEMM_GRID, 256, 0, stream>>>(abuf, hbuf, wlb, bl, wrb, abuf, 1, 0);
  // layer 1: h1 = abuf; agg -> hbuf; h2 = hbuf (in place)
  agg3_kernel<<<NBIN, 256, 0, stream>>>(abuf, hbuf, binoff, ebuf2);
  mfma_gemm_kernel<<<GEMM_GRID, 256, 0, stream>>>(hbuf, abuf, wlb + HD * HD, bl + HD, wrb + HD * HD, hbuf, 1, 0);
  // layer 2: h2 = hbuf; agg -> abuf; final = d_out (f32, no relu); ebuf dead here
  agg3_kernel<<<NBIN, 256, 0, stream>>>(hbuf, abuf, binoff, ebuf2);
  mfma_gemm_kernel<<<GEMM_GRID, 256, 0, stream>>>(abuf, hbuf, wlb + 2 * HD * HD, bl + 2 * HD, wrb + 2 * HD * HD, out, 0, 1);
}